// Round 10
// baseline (39.855 us; speedup 1.0000x reference)
//
#include <hip/hip_runtime.h>
#include <hip/hip_bf16.h>

// Cost volume: cost[b,i,h,w] = mean_c f1[b,c,h,w] * f2[b,c,h,w-i], i in [0,64), 0 if w<i.
// B=4, C=128, H=128, W=256, lvls=64. fp32 in/out, bf16 MFMA compute.
//
// R10: split each work unit (b,h,wt) across TWO waves to double wave count
// (8192 waves = 32/CU grid cap vs 16 before; occupancy was grid-limited).
//   wave0: p-tiles tp=wt-1, wt  (2 MFMA chains, 3 tile-loads)
//   wave1: p-tile  tp=wt-2      (1 MFMA chain, 2 tile-loads; idle for wt<2)
// Output cells (i,w) map to a unique p=w-i, so the waves scatter DISJOINT
// cells of one shared 8 KB strip [64 i][32 w]; __syncthreads orders
// zero-fill -> scatter -> cooperative nt-store. Per-wave serial load
// latency ~halves; traffic unchanged. Chunked XCD swizzle as before.

#define BDIM 4
#define CDIM 128
#define HDIM 128
#define WDIM 256
#define LVLS 64
#define HW   (HDIM * WDIM)          // 32768
#define CHW  (CDIM * HDIM * WDIM)   // 4194304
#define NWORK (BDIM * HDIM * 8)     // 4096 work units = 4096 blocks

typedef short    bf16x8 __attribute__((ext_vector_type(8)));
typedef float    f32x16 __attribute__((ext_vector_type(16)));
typedef float    f32x4  __attribute__((ext_vector_type(4)));

__device__ __forceinline__ short f2bf(float f) {
    __hip_bfloat16 h = __float2bfloat16(f);
    return __builtin_bit_cast(short, h);
}

__global__ __launch_bounds__(128, 8) void cost_volume_kernel(
    const float* __restrict__ f1, const float* __restrict__ f2,
    float* __restrict__ out)
{
    __shared__ float strip[LVLS * 32];   // 8 KiB, shared by the block's 2 waves

    const int tid  = threadIdx.x;
    const int lane = tid & 63;
    const int wv   = tid >> 6;           // 0: heavy wave, 1: light wave

    // chunked XCD swizzle (4096 blocks, 8 XCDs, 512-unit chunks)
    const int bid  = blockIdx.x;
    const int unit = (bid & 7) * (NWORK / 8) + (bid >> 3);

    const int wt = unit & 7;             // w-tile 0..7
    const int h  = (unit >> 3) & (HDIM - 1);
    const int b  = unit >> 10;           // 0..3

    const float* __restrict__ f1bh = f1 + (size_t)b * CHW + (size_t)h * WDIM;
    const float* __restrict__ f2bh = f2 + (size_t)b * CHW + (size_t)h * WDIM;

    const int wl    = lane & 31;
    const int wglob = wt * 32 + wl;
    const int koff  = (lane >> 5) * 8;

    f32x16 accA = (f32x16)0.0f, accB = (f32x16)0.0f;

    if (wv == 0) {
        // tiles tp = wt-1 (accA, clamped for wt=0) and tp = wt (accB)
        const int ca = ((wt - 1 < 0) ? 0 : wt - 1) * 32 + wl;
        const int cb = wt * 32 + wl;
        const float* pB  = f1bh + (size_t)koff * HW + wglob;
        const float* pAa = f2bh + (size_t)koff * HW + ca;
        const float* pAb = f2bh + (size_t)koff * HW + cb;

        #pragma unroll
        for (int kk = 0; kk < 8; ++kk) {
            const size_t kb = (size_t)(kk * 16) * HW;
            float rb[8], raa[8], rab[8];
            #pragma unroll
            for (int j = 0; j < 8; ++j) rb[j]  = pB [kb + (size_t)j * HW];
            #pragma unroll
            for (int j = 0; j < 8; ++j) raa[j] = pAa[kb + (size_t)j * HW];
            #pragma unroll
            for (int j = 0; j < 8; ++j) rab[j] = pAb[kb + (size_t)j * HW];

            bf16x8 fb, faa, fab;
            #pragma unroll
            for (int j = 0; j < 8; ++j) {
                fb[j]  = f2bf(rb[j]);
                faa[j] = f2bf(raa[j]);
                fab[j] = f2bf(rab[j]);
            }
            accA = __builtin_amdgcn_mfma_f32_32x32x16_bf16(faa, fb, accA, 0, 0, 0);
            accB = __builtin_amdgcn_mfma_f32_32x32x16_bf16(fab, fb, accB, 0, 0, 0);
        }
    } else if (wt >= 2) {
        // tile tp = wt-2 (accA); wt<2 -> tile invalid, skip compute entirely
        const int ca = (wt - 2) * 32 + wl;
        const float* pB  = f1bh + (size_t)koff * HW + wglob;
        const float* pAa = f2bh + (size_t)koff * HW + ca;

        #pragma unroll
        for (int kk = 0; kk < 8; ++kk) {
            const size_t kb = (size_t)(kk * 16) * HW;
            float rb[8], raa[8];
            #pragma unroll
            for (int j = 0; j < 8; ++j) rb[j]  = pB [kb + (size_t)j * HW];
            #pragma unroll
            for (int j = 0; j < 8; ++j) raa[j] = pAa[kb + (size_t)j * HW];

            bf16x8 fb, faa;
            #pragma unroll
            for (int j = 0; j < 8; ++j) {
                fb[j]  = f2bf(rb[j]);
                faa[j] = f2bf(raa[j]);
            }
            accA = __builtin_amdgcn_mfma_f32_32x32x16_bf16(faa, fb, accA, 0, 0, 0);
        }
    }

    // ---- epilogue: zero-fill (split), barrier, disjoint scatter, barrier, store ----

    // zero-fill: 512 f32x4 total, each wave does 4 iterations
    #pragma unroll
    for (int it = 0; it < 4; ++it)
        reinterpret_cast<f32x4*>(strip)[(wv * 4 + it) * 64 + lane] = (f32x4)0.0f;

    __syncthreads();

    // scatter: D row = (r&3) + 8*(r>>2) + 4*(lane>>5), col = lane&31.
    // p = w - i is unique per cell -> tiles write disjoint strip cells.
    const int rbase = 4 * (lane >> 5);
    {
        const int tpA = (wv == 0) ? wt - 1 : wt - 2;
        if (tpA >= 0) {
            #pragma unroll
            for (int r = 0; r < 16; ++r) {
                const int prow = tpA * 32 + (r & 3) + 8 * (r >> 2) + rbase;
                const int i = wglob - prow;
                if (i >= 0 && i < LVLS)
                    strip[i * 32 + wl] = accA[r] * (1.0f / CDIM);
            }
        }
        if (wv == 0) {
            #pragma unroll
            for (int r = 0; r < 16; ++r) {
                const int prow = wt * 32 + (r & 3) + 8 * (r >> 2) + rbase;
                const int i = wglob - prow;
                if (i >= 0 && i < LVLS)
                    strip[i * 32 + wl] = accB[r] * (1.0f / CDIM);
            }
        }
    }

    __syncthreads();

    // store out[b][i][h][wt*32 .. +32): 512 f32x4, each wave 4 iterations;
    // each iteration reads a contiguous 1 KiB LDS span (conflict-free).
    const size_t obase = (size_t)b * LVLS * HW + (size_t)h * WDIM + wt * 32;
    #pragma unroll
    for (int it = 0; it < 4; ++it) {
        const int idx = (wv * 4 + it) * 64 + lane;   // 0..511
        const int row = idx >> 3;                    // i
        const int w4  = idx & 7;
        const f32x4 v = *reinterpret_cast<const f32x4*>(&strip[row * 32 + w4 * 4]);
        __builtin_nontemporal_store(v, reinterpret_cast<f32x4*>(out + obase + (size_t)row * HW + w4 * 4));
    }
}

extern "C" void kernel_launch(void* const* d_in, const int* in_sizes, int n_in,
                              void* d_out, int out_size, void* d_ws, size_t ws_size,
                              hipStream_t stream) {
    const float* f1 = (const float*)d_in[0];
    const float* f2 = (const float*)d_in[1];
    float* out = (float*)d_out;
    cost_volume_kernel<<<dim3(NWORK), dim3(128), 0, stream>>>(f1, f2, out);
}

// Round 11
// 30.074 us; speedup vs baseline: 1.3252x; 1.3252x over previous
//
#include <hip/hip_runtime.h>
#include <hip/hip_bf16.h>

// Cost volume: cost[b,i,h,w] = mean_c f1[b,c,h,w] * f2[b,c,h,w-i], i in [0,64), 0 if w<i.
// B=4, C=128, H=128, W=256, lvls=64. fp32 in/out, bf16 MFMA compute.
//
// FINAL (= R9, best at 29.97 us): desynchronized wave-per-work-unit, two
// independent waves per block (128 thr, 16 KB LDS = 2 private strips), zero
// cross-wave barriers. Each wave computes one (b,h,wt) unit: 3 band p-tiles
// via 32x32x16 bf16 MFMA (branch-free clamped), transposes through its
// private [64 i][32 w] LDS strip (intra-wave lgkmcnt fences for the
// float/f32x4 TBAA aliasing), nontemporal f32x4 stores. Chunked XCD swizzle
// keeps f2's 3x tile reuse inside one XCD's L2 -> cross-fabric traffic is
// compulsory-minimal (128 MB read + 32 MB write).
//
// Measured bound (R1-R10): duration is linear in L2-fill traffic at
// ~5.4 TB/s combined (R10: +33% traffic -> +33% time). Width, occupancy,
// desync, staging structure all no-ops. This kernel is at that roofline.

#define BDIM 4
#define CDIM 128
#define HDIM 128
#define WDIM 256
#define LVLS 64
#define HW   (HDIM * WDIM)          // 32768
#define CHW  (CDIM * HDIM * WDIM)   // 4194304
#define NWORK (BDIM * HDIM * 8)     // 4096 work units
#define NBLK  (NWORK / 2)           // 2048 blocks

typedef short    bf16x8 __attribute__((ext_vector_type(8)));
typedef float    f32x16 __attribute__((ext_vector_type(16)));
typedef float    f32x4  __attribute__((ext_vector_type(4)));

__device__ __forceinline__ short f2bf(float f) {
    __hip_bfloat16 h = __float2bfloat16(f);
    return __builtin_bit_cast(short, h);
}

__device__ __forceinline__ void lds_fence() {
    // order LDS phases within the wave: drain outstanding DS ops and pin the
    // compiler's schedule across the boundary (TBAA can't see the aliasing).
    asm volatile("s_waitcnt lgkmcnt(0)" ::: "memory");
    __builtin_amdgcn_sched_barrier(0);
}

__global__ __launch_bounds__(128, 8) void cost_volume_kernel(
    const float* __restrict__ f1, const float* __restrict__ f2,
    float* __restrict__ out)
{
    __shared__ float strips[2][LVLS * 32];   // 16 KiB: one private strip per wave

    const int tid  = threadIdx.x;
    const int lane = tid & 63;
    const int wv   = tid >> 6;           // wave 0/1 -> independent work units

    // chunked XCD swizzle (2048 blocks, 8 XCDs, 256-block chunks), then 2
    // consecutive work units per block (they share f2 tiles -> L2 locality).
    const int bid  = blockIdx.x;
    const int work = ((bid & 7) * (NBLK / 8) + (bid >> 3)) * 2 + wv;

    const int wt = work & 7;             // w-tile 0..7
    const int h  = (work >> 3) & (HDIM - 1);
    const int b  = work >> 10;           // 0..3

    float* strip = strips[wv];

    const float* __restrict__ f1bh = f1 + (size_t)b * CHW + (size_t)h * WDIM;
    const float* __restrict__ f2bh = f2 + (size_t)b * CHW + (size_t)h * WDIM;

    const int wl    = lane & 31;
    const int wglob = wt * 32 + wl;
    const int koff  = (lane >> 5) * 8;

    // p-tiles t=0..2 -> tp = wt-2+t; clamp invalid (computed, discarded)
    const int c0 = ((wt - 2 < 0) ? 0 : wt - 2) * 32 + wl;
    const int c1 = ((wt - 1 < 0) ? 0 : wt - 1) * 32 + wl;
    const int c2 = wt * 32 + wl;

    f32x16 acc0 = (f32x16)0.0f, acc1 = (f32x16)0.0f, acc2 = (f32x16)0.0f;

    const float* pB  = f1bh + (size_t)koff * HW + wglob;
    const float* pA0 = f2bh + (size_t)koff * HW + c0;
    const float* pA1 = f2bh + (size_t)koff * HW + c1;
    const float* pA2 = f2bh + (size_t)koff * HW + c2;

    #pragma unroll
    for (int kk = 0; kk < 8; ++kk) {
        const size_t kb = (size_t)(kk * 16) * HW;

        float rb[8], ra0[8], ra1[8], ra2[8];
        #pragma unroll
        for (int j = 0; j < 8; ++j) rb[j]  = pB [kb + (size_t)j * HW];
        #pragma unroll
        for (int j = 0; j < 8; ++j) ra0[j] = pA0[kb + (size_t)j * HW];
        #pragma unroll
        for (int j = 0; j < 8; ++j) ra1[j] = pA1[kb + (size_t)j * HW];
        #pragma unroll
        for (int j = 0; j < 8; ++j) ra2[j] = pA2[kb + (size_t)j * HW];

        bf16x8 fb, fa0, fa1, fa2;
        #pragma unroll
        for (int j = 0; j < 8; ++j) {
            fb[j]  = f2bf(rb[j]);
            fa0[j] = f2bf(ra0[j]);
            fa1[j] = f2bf(ra1[j]);
            fa2[j] = f2bf(ra2[j]);
        }

        acc0 = __builtin_amdgcn_mfma_f32_32x32x16_bf16(fa0, fb, acc0, 0, 0, 0);
        acc1 = __builtin_amdgcn_mfma_f32_32x32x16_bf16(fa1, fb, acc1, 0, 0, 0);
        acc2 = __builtin_amdgcn_mfma_f32_32x32x16_bf16(fa2, fb, acc2, 0, 0, 0);
    }

    // ---- wave-private epilogue: zero strip, scatter band, coalesced nt-store ----

    // phase 1: zero-fill the [64][32] strip (512 f32x4, 8 per lane)
    #pragma unroll
    for (int it = 0; it < 8; ++it)
        reinterpret_cast<f32x4*>(strip)[it * 64 + lane] = (f32x4)0.0f;

    lds_fence();   // WAW: zero-fill (f32x4) must land before scalar scatter

    // phase 2: scatter. D row = (r&3) + 8*(r>>2) + 4*(lane>>5), col = lane&31.
    const int rbase = 4 * (lane >> 5);
    {
        const f32x16* accs[3] = { &acc0, &acc1, &acc2 };
        #pragma unroll
        for (int t = 0; t < 3; ++t) {
            const int tp = wt - 2 + t;
            if (tp >= 0) {
                const f32x16 a = *accs[t];
                #pragma unroll
                for (int r = 0; r < 16; ++r) {
                    const int prow = tp * 32 + (r & 3) + 8 * (r >> 2) + rbase;
                    const int i = wglob - prow;   // disparity
                    if (i >= 0 && i < LVLS)
                        strip[i * 32 + wl] = a[r] * (1.0f / CDIM);
                }
            }
        }
    }

    lds_fence();   // RAW: scalar scatter must land before f32x4 store-loop reads

    // phase 3: store out[b][i][h][wt*32 .. +32). Each iter reads a contiguous
    // 1 KiB LDS span (conflict-free) and writes 8 rows x 128 B.
    const size_t obase = (size_t)b * LVLS * HW + (size_t)h * WDIM + wt * 32;
    #pragma unroll
    for (int it = 0; it < 8; ++it) {
        const int idx = it * 64 + lane;       // 0..511 f32x4s
        const int row = idx >> 3;             // i
        const int w4  = idx & 7;
        const f32x4 v = *reinterpret_cast<const f32x4*>(&strip[row * 32 + w4 * 4]);
        __builtin_nontemporal_store(v, reinterpret_cast<f32x4*>(out + obase + (size_t)row * HW + w4 * 4));
    }
}

extern "C" void kernel_launch(void* const* d_in, const int* in_sizes, int n_in,
                              void* d_out, int out_size, void* d_ws, size_t ws_size,
                              hipStream_t stream) {
    const float* f1 = (const float*)d_in[0];
    const float* f2 = (const float*)d_in[1];
    float* out = (float*)d_out;
    cost_volume_kernel<<<dim3(NBLK), dim3(128), 0, stream>>>(f1, f2, out);
}